// Round 2
// baseline (343.708 us; speedup 1.0000x reference)
//
#include <hip/hip_runtime.h>

// GNN_base: per (b,l): c = ids[b,l]; neighbors n_k = ids[b, l+d], d in {-8..-1, 1..8} (0 outside).
// e_k = edge_w[n_k==0 ? 0 : c*VOCAB+n_k]; Mn[f] = max_k e_k * emb[n_k][f] (emb row 0 is zero,
// so n_k==0 terms contribute exactly 0, same as reference).
// y[b,f] = sum_l (1-nw_c)*Mn[f] + nw_c*emb[c][f],  nw_c = node_w[c].

#define VOCAB 8000
#define FDIM  256
#define PNB   8
#define NK    16
#define BB    16
#define LL    2048
#define CHUNK 32   // l-positions per block -> grid = (64, 16) = 1024 blocks

__global__ void gnn_zero_out(float* __restrict__ out) {
    out[blockIdx.x * 256 + threadIdx.x] = 0.0f;
}

__global__ __launch_bounds__(256) void gnn_kernel(
    const int*   __restrict__ ids,      // B*L
    const float* __restrict__ emb,      // VOCAB*FDIM (row 0 == 0)
    const float* __restrict__ edge_w,   // VOCAB*VOCAB+1
    const float* __restrict__ node_w,   // VOCAB
    float*       __restrict__ out)      // B*FDIM (pre-zeroed by gnn_zero_out)
{
    __shared__ int   s_nbr[CHUNK][NK];
    __shared__ float s_ew [CHUNK][NK];
    __shared__ int   s_c  [CHUNK];
    __shared__ float s_nw [CHUNK];
    __shared__ float s_red[4][FDIM];

    const int b   = blockIdx.y;
    const int l0  = blockIdx.x * CHUNK;
    const int tid = threadIdx.x;
    const int* idrow = ids + b * LL;

    // ---- Phase 1: stage neighbor ids + edge weights for CHUNK positions ----
    // CHUNK*NK = 512 items over 256 threads = 2 independent gathers/thread (MLP).
    for (int i = tid; i < CHUNK * NK; i += 256) {
        const int ll = i >> 4;          // / NK
        const int k  = i & (NK - 1);
        const int l  = l0 + ll;
        const int d  = (k < PNB) ? (k - PNB) : (k - PNB + 1);  // {-8..-1,1..8}
        const int li = l + d;
        int n = (li >= 0 && li < LL) ? idrow[li] : 0;
        n = (n < 0) ? 0 : ((n >= VOCAB) ? (VOCAB - 1) : n);     // safety clamp
        int c = idrow[l];
        c = (c < 0) ? 0 : ((c >= VOCAB) ? (VOCAB - 1) : c);     // safety clamp
        const long long ei = (n == 0) ? 0LL : (long long)c * VOCAB + n;
        s_nbr[ll][k] = n;
        s_ew [ll][k] = edge_w[ei];
    }
    if (tid < CHUNK) {
        int c = idrow[l0 + tid];
        c = (c < 0) ? 0 : ((c >= VOCAB) ? (VOCAB - 1) : c);     // safety clamp
        s_c [tid] = c;
        s_nw[tid] = node_w[c];
    }
    __syncthreads();

    // ---- Phase 2: each wave processes one l at a time; 4 features/lane ----
    const int wave = tid >> 6;
    const int lane = tid & 63;
    const int f0   = lane << 2;

    float4 acc = make_float4(0.f, 0.f, 0.f, 0.f);
    for (int ll = wave; ll < CHUNK; ll += 4) {
        const int   c  = s_c [ll];   // LDS broadcast (same addr, all lanes) - conflict-free
        const float nw = s_nw[ll];
        float4 m = make_float4(-INFINITY, -INFINITY, -INFINITY, -INFINITY);
        #pragma unroll
        for (int k = 0; k < NK; ++k) {
            const int   n = s_nbr[ll][k];
            const float e = s_ew [ll][k];
            const float4 r = *(const float4*)(emb + (size_t)n * FDIM + f0); // 1KB/wave coalesced
            m.x = fmaxf(m.x, e * r.x);
            m.y = fmaxf(m.y, e * r.y);
            m.z = fmaxf(m.z, e * r.z);
            m.w = fmaxf(m.w, e * r.w);
        }
        const float4 rc = *(const float4*)(emb + (size_t)c * FDIM + f0);
        const float w1 = 1.0f - nw;
        acc.x += w1 * m.x + nw * rc.x;
        acc.y += w1 * m.y + nw * rc.y;
        acc.z += w1 * m.z + nw * rc.z;
        acc.w += w1 * m.w + nw * rc.w;
    }

    // ---- Cross-wave reduce in LDS, then one atomic per feature ----
    ((float4*)s_red[wave])[lane] = acc;
    __syncthreads();

    const float s = s_red[0][tid] + s_red[1][tid] + s_red[2][tid] + s_red[3][tid];
    atomicAdd(out + b * FDIM + tid, s);
}

extern "C" void kernel_launch(void* const* d_in, const int* in_sizes, int n_in,
                              void* d_out, int out_size, void* d_ws, size_t ws_size,
                              hipStream_t stream) {
    // Select inputs by element count (all four are distinct) — immune to ordering.
    const int*   ids    = nullptr;
    const float* emb    = nullptr;
    const float* edge_w = nullptr;
    const float* node_w = nullptr;
    for (int i = 0; i < n_in; ++i) {
        const long long sz = in_sizes[i];
        if      (sz == (long long)BB * LL)            ids    = (const int*)  d_in[i];
        else if (sz == (long long)VOCAB * FDIM)       emb    = (const float*)d_in[i];
        else if (sz == (long long)VOCAB * VOCAB + 1)  edge_w = (const float*)d_in[i];
        else if (sz == (long long)VOCAB)              node_w = (const float*)d_in[i];
    }
    float* out = (float*)d_out;

    // d_out is re-poisoned to 0xAA before every timed launch -> zero it with a
    // kernel (graph-capture-safe; no runtime memset APIs inside capture).
    gnn_zero_out<<<dim3(out_size / 256), dim3(256), 0, stream>>>(out);

    dim3 grid(LL / CHUNK, BB);
    gnn_kernel<<<grid, 256, 0, stream>>>(ids, emb, edge_w, node_w, out);
}

// Round 3
// 322.267 us; speedup vs baseline: 1.0665x; 1.0665x over previous
//
#include <hip/hip_runtime.h>

// GNN_base: per (b,l): c = ids[b,l]; neighbors n_k = ids[b, l+d], d in {-8..-1, 1..8} (0 outside).
// e_k = edge_w[n_k==0 ? 0 : c*VOCAB+n_k]; Mn[f] = max_k e_k * emb[n_k][f] (emb row 0 is zero,
// so n_k==0 terms contribute exactly 0). y[b,f] = sum_l (1-nw_c)*Mn[f] + nw_c*emb[c][f].
//
// Key structure: neighbor sets of consecutive l overlap — a chunk of CHUNK positions touches
// only CHUNK+16 distinct emb rows. Stage that window into LDS once (32 KB), then all 17
// row-reads per position are LDS ds_read_b128 instead of global gathers (8.5x traffic cut).

#define VOCAB 8000
#define FDIM  256
#define PNB   8
#define NK    16
#define BB    16
#define LL    2048
#define CHUNK 16              // l-positions per block
#define WIN   (CHUNK + 2*PNB) // 32 distinct emb rows per block

__global__ void gnn_zero_out(float* __restrict__ out) {
    out[blockIdx.x * 256 + threadIdx.x] = 0.0f;
}

__global__ __launch_bounds__(256) void gnn_kernel(
    const int*   __restrict__ ids,      // B*L
    const float* __restrict__ emb,      // VOCAB*FDIM (row 0 == 0)
    const float* __restrict__ edge_w,   // VOCAB*VOCAB+1
    const float* __restrict__ node_w,   // VOCAB
    float*       __restrict__ out)      // B*FDIM (pre-zeroed by gnn_zero_out)
{
    __shared__ float s_emb[WIN][FDIM];   // 32 KB staged embedding window
    __shared__ float s_ew [CHUNK][NK];   // 1 KB edge weights
    __shared__ int   s_tok[WIN];
    __shared__ float s_nw [CHUNK];
    __shared__ float s_red[4][FDIM];     // 4 KB cross-wave reduce

    const int b   = blockIdx.y;
    const int l0  = blockIdx.x * CHUNK;
    const int tid = threadIdx.x;
    const int* idrow = ids + b * LL;

    // ---- Phase A: window token ids (positions l0-8 .. l0+CHUNK+7) ----
    if (tid < WIN) {
        const int p = l0 - PNB + tid;
        int t = (p >= 0 && p < LL) ? idrow[p] : 0;
        t = (t < 0) ? 0 : ((t >= VOCAB) ? (VOCAB - 1) : t);   // safety clamp
        s_tok[tid] = t;
    }
    __syncthreads();

    // ---- Phase B: random edge-weight gathers (issue first: long latency) ----
    {   // CHUNK*NK = 256 gathers, exactly one per thread
        const int ll = tid >> 4;
        const int k  = tid & (NK - 1);
        const int n  = s_tok[ll + k + (k >= PNB ? 1 : 0)];
        const int c  = s_tok[ll + PNB];
        const long long ei = (n == 0) ? 0LL : (long long)c * VOCAB + n;
        s_ew[ll][k] = edge_w[ei];
        if (tid < CHUNK) s_nw[tid] = node_w[s_tok[tid + PNB]];
    }
    // ---- Phase B': stage WIN emb rows into LDS (coalesced float4) ----
    {   // WIN rows * 64 float4/row = 2048 float4 over 256 threads = 8 each
        #pragma unroll
        for (int j = 0; j < 8; ++j) {
            const int i    = tid + 256 * j;
            const int row  = i >> 6;          // 0..31
            const int col4 = (i & 63) << 2;   // feature offset 0..252 step 4
            const float4 v = *(const float4*)(emb + (size_t)s_tok[row] * FDIM + col4);
            *(float4*)&s_emb[row][col4] = v;
        }
    }
    __syncthreads();

    // ---- Phase C: each wave computes 4 positions from LDS ----
    const int wave = tid >> 6;
    const int lane = tid & 63;
    const int f0   = lane << 2;

    float4 acc = make_float4(0.f, 0.f, 0.f, 0.f);
    #pragma unroll
    for (int q = 0; q < CHUNK / 4; ++q) {
        const int ll = (wave << 2) + q;
        const float nw = s_nw[ll];           // LDS broadcast — conflict-free
        float4 m = make_float4(-INFINITY, -INFINITY, -INFINITY, -INFINITY);
        #pragma unroll
        for (int k = 0; k < NK; ++k) {
            const int widx = ll + k + (k >= PNB ? 1 : 0);
            const float  e = s_ew[ll][k];                      // broadcast
            const float4 r = *(const float4*)&s_emb[widx][f0]; // ds_read_b128, lane-linear
            m.x = fmaxf(m.x, e * r.x);
            m.y = fmaxf(m.y, e * r.y);
            m.z = fmaxf(m.z, e * r.z);
            m.w = fmaxf(m.w, e * r.w);
        }
        const float4 rc = *(const float4*)&s_emb[ll + PNB][f0];
        const float w1 = 1.0f - nw;
        acc.x += w1 * m.x + nw * rc.x;
        acc.y += w1 * m.y + nw * rc.y;
        acc.z += w1 * m.z + nw * rc.z;
        acc.w += w1 * m.w + nw * rc.w;
    }

    // ---- Phase D: cross-wave reduce, one atomic per feature ----
    ((float4*)s_red[wave])[lane] = acc;
    __syncthreads();

    const float s = s_red[0][tid] + s_red[1][tid] + s_red[2][tid] + s_red[3][tid];
    atomicAdd(out + b * FDIM + tid, s);
}

extern "C" void kernel_launch(void* const* d_in, const int* in_sizes, int n_in,
                              void* d_out, int out_size, void* d_ws, size_t ws_size,
                              hipStream_t stream) {
    // Select inputs by element count (all four distinct) — immune to ordering.
    const int*   ids    = nullptr;
    const float* emb    = nullptr;
    const float* edge_w = nullptr;
    const float* node_w = nullptr;
    for (int i = 0; i < n_in; ++i) {
        const long long sz = in_sizes[i];
        if      (sz == (long long)BB * LL)            ids    = (const int*)  d_in[i];
        else if (sz == (long long)VOCAB * FDIM)       emb    = (const float*)d_in[i];
        else if (sz == (long long)VOCAB * VOCAB + 1)  edge_w = (const float*)d_in[i];
        else if (sz == (long long)VOCAB)              node_w = (const float*)d_in[i];
    }
    float* out = (float*)d_out;

    // d_out is re-poisoned to 0xAA before every timed launch -> zero via kernel
    // (graph-capture-safe).
    gnn_zero_out<<<dim3(out_size / 256), dim3(256), 0, stream>>>(out);

    dim3 grid(LL / CHUNK, BB);
    gnn_kernel<<<grid, 256, 0, stream>>>(ids, emb, edge_w, node_w, out);
}

// Round 4
// 318.741 us; speedup vs baseline: 1.0783x; 1.0111x over previous
//
#include <hip/hip_runtime.h>

// GNN_base: per (b,l): c = ids[b,l]; neighbors n_k = ids[b, l+d], d in {-8..-1, 1..8} (0 outside).
// e_k = edge_w[n_k==0 ? 0 : c*VOCAB+n_k]; Mn[f] = max_k e_k * emb[n_k][f] (emb row 0 is zero,
// so n_k==0 terms contribute exactly 0). y[b,f] = sum_l (1-nw_c)*Mn[f] + nw_c*emb[c][f].
//
// Structure: a chunk of CHUNK positions touches only CHUNK+16 distinct emb rows -> stage the
// window in LDS once. Phase C: each wave owns 4 CONSECUTIVE positions; their union window is
// 20 rows, each read ONCE (ds_read_b128) and applied to all affected positions with
// compile-time (j,q) conditions — 3.6x fewer LDS row reads than position-major.

#define VOCAB 8000
#define FDIM  256
#define PNB   8
#define NK    16
#define BB    16
#define LL    2048
#define CHUNK 16              // l-positions per block
#define WIN   (CHUNK + 2*PNB) // 32 distinct emb rows per block

__global__ void gnn_zero_out(float* __restrict__ out) {
    out[blockIdx.x * 256 + threadIdx.x] = 0.0f;
}

__global__ __launch_bounds__(256) void gnn_kernel(
    const int*   __restrict__ ids,      // B*L
    const float* __restrict__ emb,      // VOCAB*FDIM (row 0 == 0)
    const float* __restrict__ edge_w,   // VOCAB*VOCAB+1
    const float* __restrict__ node_w,   // VOCAB
    float*       __restrict__ out)      // B*FDIM (pre-zeroed by gnn_zero_out)
{
    __shared__ float s_emb[WIN][FDIM];   // 32 KB staged embedding window
    __shared__ float s_ew [CHUNK][NK];   // 1 KB edge weights
    __shared__ int   s_tok[WIN];
    __shared__ float s_nw [CHUNK];
    __shared__ float s_red[4][FDIM];     // 4 KB cross-wave reduce

    const int b   = blockIdx.y;
    const int l0  = blockIdx.x * CHUNK;
    const int tid = threadIdx.x;
    const int* idrow = ids + b * LL;

    // ---- Phase A: window token ids (positions l0-8 .. l0+CHUNK+7) ----
    if (tid < WIN) {
        const int p = l0 - PNB + tid;
        int t = (p >= 0 && p < LL) ? idrow[p] : 0;
        t = (t < 0) ? 0 : ((t >= VOCAB) ? (VOCAB - 1) : t);   // safety clamp
        s_tok[tid] = t;
    }
    __syncthreads();

    // ---- Phase B: random edge-weight gathers (issue first: long latency).
    // Nontemporal: these lines have ZERO reuse — don't evict emb from L2/L3.
    {   // CHUNK*NK = 256 gathers, exactly one per thread
        const int ll = tid >> 4;
        const int k  = tid & (NK - 1);
        const int n  = s_tok[ll + k + (k >= PNB ? 1 : 0)];
        const int c  = s_tok[ll + PNB];
        const long long ei = (n == 0) ? 0LL : (long long)c * VOCAB + n;
        s_ew[ll][k] = __builtin_nontemporal_load(edge_w + ei);
        if (tid < CHUNK) s_nw[tid] = node_w[s_tok[tid + PNB]];
    }
    // ---- Phase B': stage WIN emb rows into LDS (each wave: one full row per j) ----
    {   // WIN rows * 64 float4/row = 2048 float4 over 256 threads = 8 each
        #pragma unroll
        for (int j = 0; j < 8; ++j) {
            const int i    = tid + 256 * j;
            const int row  = i >> 6;          // wave w, iter j -> row w + 4j
            const int col4 = (i & 63) << 2;
            const float4 v = *(const float4*)(emb + (size_t)s_tok[row] * FDIM + col4);
            *(float4*)&s_emb[row][col4] = v;
        }
    }
    __syncthreads();

    // ---- Phase C: wave w owns positions 4w..4w+3; union window = rows 4w..4w+19.
    // Each row read once; applied to affected positions with compile-time conditions.
    const int wave = tid >> 6;
    const int lane = tid & 63;
    const int f0   = lane << 2;
    const int base = wave << 2;

    float4 m[4], rc[4];
    #pragma unroll
    for (int q = 0; q < 4; ++q)
        m[q] = make_float4(-INFINITY, -INFINITY, -INFINITY, -INFINITY);

    #pragma unroll
    for (int j = 0; j < 20; ++j) {
        const float4 r = *(const float4*)&s_emb[base + j][f0];  // ds_read_b128, once
        #pragma unroll
        for (int q = 0; q < 4; ++q) {
            const int d = j - q;              // compile-time per (j,q)
            if (d < 0 || d > 16) continue;    // outside this position's window
            if (d == 8) { rc[q] = r; continue; }  // center row: capture for blend
            const int   k = (d < 8) ? d : d - 1;  // neighbor slot
            const float e = s_ew[base + q][k];    // LDS broadcast — conflict-free
            m[q].x = fmaxf(m[q].x, e * r.x);
            m[q].y = fmaxf(m[q].y, e * r.y);
            m[q].z = fmaxf(m[q].z, e * r.z);
            m[q].w = fmaxf(m[q].w, e * r.w);
        }
    }

    float4 acc = make_float4(0.f, 0.f, 0.f, 0.f);
    #pragma unroll
    for (int q = 0; q < 4; ++q) {
        const float nw = s_nw[base + q];
        const float w1 = 1.0f - nw;
        acc.x += w1 * m[q].x + nw * rc[q].x;
        acc.y += w1 * m[q].y + nw * rc[q].y;
        acc.z += w1 * m[q].z + nw * rc[q].z;
        acc.w += w1 * m[q].w + nw * rc[q].w;
    }

    // ---- Phase D: cross-wave reduce, one atomic per feature ----
    ((float4*)s_red[wave])[lane] = acc;
    __syncthreads();

    const float s = s_red[0][tid] + s_red[1][tid] + s_red[2][tid] + s_red[3][tid];
    atomicAdd(out + b * FDIM + tid, s);
}

extern "C" void kernel_launch(void* const* d_in, const int* in_sizes, int n_in,
                              void* d_out, int out_size, void* d_ws, size_t ws_size,
                              hipStream_t stream) {
    // Select inputs by element count (all four distinct) — immune to ordering.
    const int*   ids    = nullptr;
    const float* emb    = nullptr;
    const float* edge_w = nullptr;
    const float* node_w = nullptr;
    for (int i = 0; i < n_in; ++i) {
        const long long sz = in_sizes[i];
        if      (sz == (long long)BB * LL)            ids    = (const int*)  d_in[i];
        else if (sz == (long long)VOCAB * FDIM)       emb    = (const float*)d_in[i];
        else if (sz == (long long)VOCAB * VOCAB + 1)  edge_w = (const float*)d_in[i];
        else if (sz == (long long)VOCAB)              node_w = (const float*)d_in[i];
    }
    float* out = (float*)d_out;

    // d_out is re-poisoned to 0xAA before every timed launch -> zero via kernel
    // (graph-capture-safe).
    gnn_zero_out<<<dim3(out_size / 256), dim3(256), 0, stream>>>(out);

    dim3 grid(LL / CHUNK, BB);
    gnn_kernel<<<grid, 256, 0, stream>>>(ids, emb, edge_w, node_w, out);
}

// Round 5
// 317.489 us; speedup vs baseline: 1.0826x; 1.0039x over previous
//
#include <hip/hip_runtime.h>

// GNN_base: per (b,l): c = ids[b,l]; neighbors n_k = ids[b, l+d], d in {-8..-1, 1..8} (0 outside).
// e_k = edge_w[n_k==0 ? 0 : c*VOCAB+n_k]; Mn[f] = max_k e_k * emb[n_k][f] (emb row 0 is zero,
// so n_k==0 terms contribute exactly 0). y[b,f] = sum_l (1-nw_c)*Mn[f] + nw_c*emb[c][f].
//
// Structure: a chunk of CHUNK positions touches only CHUNK+16 distinct emb rows -> stage the
// window in LDS once. Each wave owns 4 consecutive positions; union window = 20 rows, each
// read once (ds_read_b128), applied via compile-time (j,q) conditions.
// Epilogue: NO atomics — per-block partial rows to d_ws, tiny second kernel reduces 128
// partials per output element (2 MB, L2-resident). d_out fully overwritten -> no zero kernel.

#define VOCAB 8000
#define FDIM  256
#define PNB   8
#define NK    16
#define BB    16
#define LL    2048
#define CHUNK 16              // l-positions per block
#define WIN   (CHUNK + 2*PNB) // 32 distinct emb rows per block
#define NCHUNK (LL / CHUNK)   // 128 blocks per batch row

__global__ __launch_bounds__(256) void gnn_kernel(
    const int*   __restrict__ ids,      // B*L
    const float* __restrict__ emb,      // VOCAB*FDIM (row 0 == 0)
    const float* __restrict__ edge_w,   // VOCAB*VOCAB+1
    const float* __restrict__ node_w,   // VOCAB
    float*       __restrict__ ws)       // partials: [BB][NCHUNK][FDIM]
{
    __shared__ float s_emb[WIN][FDIM];   // 32 KB staged embedding window
    __shared__ float s_ew [CHUNK][NK];   // 1 KB edge weights
    __shared__ int   s_tok[WIN];
    __shared__ float s_nw [CHUNK];
    __shared__ float s_red[4][FDIM];     // 4 KB cross-wave reduce

    const int b   = blockIdx.y;
    const int l0  = blockIdx.x * CHUNK;
    const int tid = threadIdx.x;
    const int* idrow = ids + b * LL;

    // ---- Phase A: window token ids (positions l0-8 .. l0+CHUNK+7) ----
    if (tid < WIN) {
        const int p = l0 - PNB + tid;
        int t = (p >= 0 && p < LL) ? idrow[p] : 0;
        t = (t < 0) ? 0 : ((t >= VOCAB) ? (VOCAB - 1) : t);   // safety clamp
        s_tok[tid] = t;
    }
    __syncthreads();

    // ---- Phase B: random edge-weight gathers (issue first: long latency).
    // Nontemporal: zero reuse — don't evict emb from L2/L3.
    {   // CHUNK*NK = 256 gathers, exactly one per thread
        const int ll = tid >> 4;
        const int k  = tid & (NK - 1);
        const int n  = s_tok[ll + k + (k >= PNB ? 1 : 0)];
        const int c  = s_tok[ll + PNB];
        const long long ei = (n == 0) ? 0LL : (long long)c * VOCAB + n;
        s_ew[ll][k] = __builtin_nontemporal_load(edge_w + ei);
        if (tid < CHUNK) s_nw[tid] = node_w[s_tok[tid + PNB]];
    }
    // ---- Phase B': stage WIN emb rows into LDS (coalesced float4) ----
    {   // WIN rows * 64 float4/row = 2048 float4 over 256 threads = 8 each
        #pragma unroll
        for (int j = 0; j < 8; ++j) {
            const int i    = tid + 256 * j;
            const int row  = i >> 6;
            const int col4 = (i & 63) << 2;
            const float4 v = *(const float4*)(emb + (size_t)s_tok[row] * FDIM + col4);
            *(float4*)&s_emb[row][col4] = v;
        }
    }
    __syncthreads();

    // ---- Phase C: wave w owns positions 4w..4w+3; union window = rows 4w..4w+19.
    const int wave = tid >> 6;
    const int lane = tid & 63;
    const int f0   = lane << 2;
    const int base = wave << 2;

    float4 m[4], rc[4];
    #pragma unroll
    for (int q = 0; q < 4; ++q)
        m[q] = make_float4(-INFINITY, -INFINITY, -INFINITY, -INFINITY);

    #pragma unroll
    for (int j = 0; j < 20; ++j) {
        const float4 r = *(const float4*)&s_emb[base + j][f0];  // ds_read_b128, once
        #pragma unroll
        for (int q = 0; q < 4; ++q) {
            const int d = j - q;                  // compile-time per (j,q)
            if (d < 0 || d > 16) continue;        // outside this position's window
            if (d == 8) { rc[q] = r; continue; }  // center row: capture for blend
            const int   k = (d < 8) ? d : d - 1;  // neighbor slot
            const float e = s_ew[base + q][k];    // LDS broadcast — conflict-free
            m[q].x = fmaxf(m[q].x, e * r.x);
            m[q].y = fmaxf(m[q].y, e * r.y);
            m[q].z = fmaxf(m[q].z, e * r.z);
            m[q].w = fmaxf(m[q].w, e * r.w);
        }
    }

    float4 acc = make_float4(0.f, 0.f, 0.f, 0.f);
    #pragma unroll
    for (int q = 0; q < 4; ++q) {
        const float nw = s_nw[base + q];
        const float w1 = 1.0f - nw;
        acc.x += w1 * m[q].x + nw * rc[q].x;
        acc.y += w1 * m[q].y + nw * rc[q].y;
        acc.z += w1 * m[q].z + nw * rc[q].z;
        acc.w += w1 * m[q].w + nw * rc[q].w;
    }

    // ---- Phase D: cross-wave reduce in LDS, coalesced partial-row store (NO atomics) ----
    ((float4*)s_red[wave])[lane] = acc;
    __syncthreads();

    const float s = s_red[0][tid] + s_red[1][tid] + s_red[2][tid] + s_red[3][tid];
    ws[((size_t)b * NCHUNK + blockIdx.x) * FDIM + tid] = s;
}

__global__ __launch_bounds__(256) void gnn_reduce(
    const float* __restrict__ ws,   // [BB][NCHUNK][FDIM] partials
    float*       __restrict__ out)  // [BB][FDIM]
{
    const int b = blockIdx.x;
    const int f = threadIdx.x;
    const float* p = ws + (size_t)b * NCHUNK * FDIM + f;
    float s = 0.0f;
    #pragma unroll 8
    for (int c = 0; c < NCHUNK; ++c)
        s += p[(size_t)c * FDIM];
    out[b * FDIM + f] = s;
}

extern "C" void kernel_launch(void* const* d_in, const int* in_sizes, int n_in,
                              void* d_out, int out_size, void* d_ws, size_t ws_size,
                              hipStream_t stream) {
    // Select inputs by element count (all four distinct) — immune to ordering.
    const int*   ids    = nullptr;
    const float* emb    = nullptr;
    const float* edge_w = nullptr;
    const float* node_w = nullptr;
    for (int i = 0; i < n_in; ++i) {
        const long long sz = in_sizes[i];
        if      (sz == (long long)BB * LL)            ids    = (const int*)  d_in[i];
        else if (sz == (long long)VOCAB * FDIM)       emb    = (const float*)d_in[i];
        else if (sz == (long long)VOCAB * VOCAB + 1)  edge_w = (const float*)d_in[i];
        else if (sz == (long long)VOCAB)              node_w = (const float*)d_in[i];
    }
    float* out = (float*)d_out;
    float* ws  = (float*)d_ws;   // 2 MB of the scratch; fully written before read

    dim3 grid(NCHUNK, BB);
    gnn_kernel<<<grid, 256, 0, stream>>>(ids, emb, edge_w, node_w, ws);
    gnn_reduce<<<dim3(BB), 256, 0, stream>>>(ws, out);
}